// Round 4
// baseline (2772.339 us; speedup 1.0000x reference)
//
#include <hip/hip_runtime.h>

#define TT   8192
#define DDIM 2048
#define HDIM 7168
#define NEXP 8
#define MT   32                 // max M-tiles per expert (8192/256)
#define NT1  (HDIM / 128)       // 56 n-tiles for gemm1 (128 h1 + 128 h3 cols each)
#define NT2  (DDIM / 256)       // 8 n-tiles for gemm2

typedef __attribute__((ext_vector_type(8))) short bf16x8;
typedef __attribute__((ext_vector_type(4))) short short4v;
typedef __attribute__((ext_vector_type(4))) float f32x4;

__device__ __forceinline__ unsigned short f2bf(float f) {
  unsigned int u = __builtin_bit_cast(unsigned int, f);
  u += 0x7fffu + ((u >> 16) & 1u);   // RNE
  return (unsigned short)(u >> 16);
}

__device__ __forceinline__ void gload_lds16(const void* gp, void* lp) {
  __builtin_amdgcn_global_load_lds((__attribute__((address_space(1))) void*)gp,
                                   (__attribute__((address_space(3))) void*)lp,
                                   16, 0, 0);
}

__device__ __forceinline__ void mfma16(f32x4& c, bf16x8 a, bf16x8 b) {
  asm("v_mfma_f32_16x16x32_bf16 %0, %1, %2, %0" : "+v"(c) : "v"(a), "v"(b));
}

// ---------------- fp32 -> bf16 elementwise ----------------
__global__ __launch_bounds__(256) void cvt_bf16_kernel(const float* __restrict__ src,
                                                       unsigned short* __restrict__ dst,
                                                       long n4) {
  long i = (long)blockIdx.x * 256 + threadIdx.x;
  long stride = (long)gridDim.x * 256;
  for (; i < n4; i += stride) {
    float4 v = ((const float4*)src)[i];
    short4v s;
    s[0] = (short)f2bf(v.x); s[1] = (short)f2bf(v.y);
    s[2] = (short)f2bf(v.z); s[3] = (short)f2bf(v.w);
    ((short4v*)dst)[i] = s;
  }
}

// ---------------- gate ----------------
__global__ __launch_bounds__(256) void gate_kernel(const float* __restrict__ x,
                                                   const float* __restrict__ gw,
                                                   int* __restrict__ route_e,
                                                   float* __restrict__ route_w,
                                                   int* __restrict__ counts) {
  int t = blockIdx.x;
  int tid = threadIdx.x;
  const float* xr = x + (size_t)t * DDIM;
  float p[NEXP];
#pragma unroll
  for (int e = 0; e < NEXP; ++e) p[e] = 0.f;
#pragma unroll
  for (int c = 0; c < DDIM / (256 * 4); ++c) {
    int d = (c * 256 + tid) * 4;
    float4 xv = *(const float4*)(xr + d);
#pragma unroll
    for (int e = 0; e < NEXP; ++e) {
      float4 wv = *(const float4*)(gw + (size_t)e * DDIM + d);
      p[e] += xv.x * wv.x + xv.y * wv.y + xv.z * wv.z + xv.w * wv.w;
    }
  }
  __shared__ float red[NEXP][4];
  int lane = tid & 63, wid = tid >> 6;
#pragma unroll
  for (int e = 0; e < NEXP; ++e) {
    float v = p[e];
    for (int o = 32; o > 0; o >>= 1) v += __shfl_down(v, o);
    if (lane == 0) red[e][wid] = v;
  }
  __syncthreads();
  if (tid == 0) {
    float lg[NEXP];
#pragma unroll
    for (int e = 0; e < NEXP; ++e) lg[e] = red[e][0] + red[e][1] + red[e][2] + red[e][3];
    int i0 = 0;
#pragma unroll
    for (int e = 1; e < NEXP; ++e) if (lg[e] > lg[i0]) i0 = e;
    int i1 = -1;
#pragma unroll
    for (int e = 0; e < NEXP; ++e) {
      if (e == i0) continue;
      if (i1 < 0 || lg[e] > lg[i1]) i1 = e;
    }
    float w0 = 1.f / (1.f + __expf(lg[i1] - lg[i0]));
    float w1 = 1.f - w0;
    route_e[t * 2 + 0] = i0;  route_e[t * 2 + 1] = i1;
    route_w[t * 2 + 0] = w0;  route_w[t * 2 + 1] = w1;
    atomicAdd(&counts[i0], 1);
    atomicAdd(&counts[i1], 1);
  }
}

__global__ void scan_kernel(const int* __restrict__ counts, int* __restrict__ offsets,
                            int* __restrict__ cursor) {
  if (threadIdx.x == 0 && blockIdx.x == 0) {
    int o = 0;
    for (int e = 0; e < NEXP; ++e) { offsets[e] = o; cursor[e] = o; o += counts[e]; }
  }
}

__global__ __launch_bounds__(256) void scatter_kernel(const int* __restrict__ route_e,
                                                      const float* __restrict__ route_w,
                                                      int* __restrict__ cursor,
                                                      int* __restrict__ tok_list,
                                                      float* __restrict__ tok_w) {
  int t = blockIdx.x * 256 + threadIdx.x;
  if (t >= TT) return;
#pragma unroll
  for (int s = 0; s < 2; ++s) {
    int e = route_e[t * 2 + s];
    int p = atomicAdd(&cursor[e], 1);
    tok_list[p] = t;
    tok_w[p] = route_w[t * 2 + s];
  }
}

// ---------------- w2 [H,D] fp32 -> w2t [D,H] bf16 ----------------
__global__ __launch_bounds__(256) void transpose_w2_kernel(const float* __restrict__ w2,
                                                           unsigned short* __restrict__ w2t,
                                                           int expert_fixed) {
  int e = expert_fixed >= 0 ? expert_fixed : (int)blockIdx.z;
  const float* src = w2 + (size_t)e * HDIM * DDIM;
  unsigned short* dst = w2t + (expert_fixed >= 0 ? (size_t)0 : (size_t)e * DDIM * HDIM);
  int h0 = blockIdx.x * 64, d0 = blockIdx.y * 64;
  __shared__ __align__(8) unsigned short tile[64 * 66];
  int tid = threadIdx.x;
  int hr = tid >> 2;
#pragma unroll
  for (int j = 0; j < 4; ++j) {
    int f4 = (tid & 3) + j * 4;
    float4 v = *(const float4*)(src + (size_t)(h0 + hr) * DDIM + d0 + f4 * 4);
    unsigned int lo = (unsigned int)f2bf(v.x) | ((unsigned int)f2bf(v.y) << 16);
    unsigned int hi = (unsigned int)f2bf(v.z) | ((unsigned int)f2bf(v.w) << 16);
    char* bp = (char*)tile + hr * 132 + f4 * 8;
    *(unsigned int*)bp = lo;
    *(unsigned int*)(bp + 4) = hi;
  }
  __syncthreads();
  int dr = tid >> 2;
  int hbase = (tid & 3) * 16;
  unsigned short vals[16];
#pragma unroll
  for (int i = 0; i < 16; ++i)
    vals[i] = *(unsigned short*)((char*)tile + (hbase + i) * 132 + dr * 2);
  unsigned short* op = dst + (size_t)(d0 + dr) * HDIM + h0 + hbase;
#pragma unroll
  for (int j = 0; j < 4; ++j) {
    short4v s;
    s[0] = (short)vals[j * 4 + 0]; s[1] = (short)vals[j * 4 + 1];
    s[2] = (short)vals[j * 4 + 2]; s[3] = (short)vals[j * 4 + 3];
    *(short4v*)(op + j * 4) = s;
  }
}

// =====================================================================
// Shared tile geometry (both GEMMs): 256x256 tile, BK=64 stored as two
// 256x32 sub-tiles (row stride 64B, XOR-swizzled chunks: phys chunk p
// holds logical chunk p ^ ((row>>1)&3)).  8 waves (2M x 4N), per-wave
// output 128x64.  Drain schedule: one __syncthreads per K-tile (implicit
// vmcnt(0)+lgkmcnt(0)) -- provably race-free.
// =====================================================================

// =====================================================================
// GEMM1: g = silu(Xe w1^T) * (Xe w3^T).  B rows 0..127 = w1 cols,
// 128..255 = w3 cols; epilogue exchanges h1 via LDS.
// =====================================================================
__global__ __launch_bounds__(512, 2) void gemm1_kernel(
    const unsigned short* __restrict__ xbf, const unsigned short* __restrict__ w1b,
    const unsigned short* __restrict__ w3b, const int* __restrict__ tok_list,
    const int* __restrict__ counts, const int* __restrict__ offsets,
    unsigned short* __restrict__ g, int expert_fixed) {
  __shared__ __align__(16) char smem[133120];   // 2 x 64KB ring + epi hb[256][130] f32
  constexpr int NK = DDIM / 64;                 // 32

  int nwg = gridDim.x;
  int orig = blockIdx.x;
  int wg = (orig & 7) * (nwg >> 3) + (orig >> 3);   // bijective XCD swizzle (nwg%8==0)
  int mt = wg & (MT - 1);
  int rem = wg >> 5;
  int nt = rem % NT1;
  int e = expert_fixed >= 0 ? expert_fixed : rem / NT1;

  int cnt = counts[e];
  int mbase = mt * 256;
  if (mbase >= cnt) return;
  int off = offsets[e];
  int gshift = expert_fixed >= 0 ? 0 : off;
  int rows = cnt - mbase; if (rows > 256) rows = 256;

  const unsigned short* w1e = expert_fixed >= 0 ? w1b : w1b + (size_t)e * HDIM * DDIM;
  const unsigned short* w3e = expert_fixed >= 0 ? w3b : w3b + (size_t)e * HDIM * DDIM;

  int tid = threadIdx.x, lane = tid & 63, wid = tid >> 6;
  int wr = wid >> 2, wc = wid & 3;

  // ---- staging sources: per gload, wave covers 16 rows x 64B ----
  // lane l -> row l>>2, phys chunk l&3, logical src chunk (l&3)^((l>>3)&3)
  int r16 = lane >> 2;                          // row within 16-row group
  int csrc = (lane & 3) ^ ((lane >> 3) & 3);    // pre-swizzled source chunk
  const char* asrc[2]; const char* bsrc[2];
#pragma unroll
  for (int j = 0; j < 2; ++j) {
    int r = wid * 32 + j * 16 + r16;            // tile row 0..255
    int m = mbase + r; if (m > cnt - 1) m = cnt - 1;
    int tok = tok_list[off + m];
    asrc[j] = (const char*)xbf + (size_t)tok * (DDIM * 2) + csrc * 16;
    const char* base = (r < 128)
        ? (const char*)w1e + (size_t)(nt * 128 + r) * (DDIM * 2)
        : (const char*)w3e + (size_t)(nt * 128 + r - 128) * (DDIM * 2);
    bsrc[j] = base + csrc * 16;
  }
  // ---- fragment read offsets (lane-constant) ----
  int rowA = (wr * 128 + (lane & 15)) * 64;
  int rowB = (wc * 64  + (lane & 15)) * 64;
  int ckr  = (((lane >> 4) ^ ((lane >> 1) & 3)) * 16);

  f32x4 zv = {0.f, 0.f, 0.f, 0.f};
  f32x4 acc[8][4];
#pragma unroll
  for (int m = 0; m < 8; ++m)
#pragma unroll
    for (int n = 0; n < 4; ++n) acc[m][n] = zv;

  // LDS buffer b (64KB): A-sub0 | A-sub1 | B-sub0 | B-sub1 (16KB each)
  auto STAGE = [&](int buf, int kt) {
    char* base = smem + buf * 65536;
    size_t ko = (size_t)kt * 128;
#pragma unroll
    for (int s = 0; s < 2; ++s)
#pragma unroll
      for (int j = 0; j < 2; ++j) {
        char* dA = base + s * 16384 + wid * 2048 + j * 1024;
        char* dB = base + 32768 + s * 16384 + wid * 2048 + j * 1024;
        gload_lds16(asrc[j] + ko + s * 64, dA);
        gload_lds16(bsrc[j] + ko + s * 64, dB);
      }
  };

  STAGE(0, 0);
  __syncthreads();
  int buf = 0;
  for (int kt = 0; kt < NK; ++kt) {
    if (kt + 1 < NK) STAGE(buf ^ 1, kt + 1);
    char* Ab = smem + buf * 65536;
    char* Bb = Ab + 32768;
#pragma unroll
    for (int ks = 0; ks < 2; ++ks) {
      bf16x8 af[8], bfr[4];
#pragma unroll
      for (int mi = 0; mi < 8; ++mi)
        af[mi] = *(const bf16x8*)(Ab + ks * 16384 + rowA + mi * 1024 + ckr);
#pragma unroll
      for (int ni = 0; ni < 4; ++ni)
        bfr[ni] = *(const bf16x8*)(Bb + ks * 16384 + rowB + ni * 1024 + ckr);
      __builtin_amdgcn_s_setprio(1);
#pragma unroll
      for (int ni = 0; ni < 4; ++ni)
#pragma unroll
        for (int mi = 0; mi < 8; ++mi) mfma16(acc[mi][ni], af[mi], bfr[ni]);
      __builtin_amdgcn_s_setprio(0);
    }
    __syncthreads();    // full drain: publishes kt+1, retires all reads of kt
    buf ^= 1;
  }

  // ---- epilogue: h1 (wc<2) -> LDS; h3 (wc>=2) computes g = silu(h1)*h3 ----
  float* hb = (float*)smem;                       // [256][130] f32
  if (wc < 2) {
#pragma unroll
    for (int m = 0; m < 8; ++m)
#pragma unroll
      for (int q = 0; q < 4; ++q) {
        int row = wr * 128 + m * 16 + (lane >> 4) * 4 + q;
        int col = wc * 64 + (lane & 15);
#pragma unroll
        for (int n = 0; n < 4; ++n)
          hb[row * 130 + col + n * 16] = acc[m][n][q];
      }
  }
  __syncthreads();
  if (wc >= 2) {
#pragma unroll
    for (int m = 0; m < 8; ++m)
#pragma unroll
      for (int q = 0; q < 4; ++q) {
        int row = wr * 128 + m * 16 + (lane >> 4) * 4 + q;
        if (row >= rows) continue;
        size_t grow = (size_t)(mbase + row + gshift);
        int colbase = (wc - 2) * 64 + (lane & 15);
        unsigned short* gp = g + grow * HDIM + nt * 128 + colbase;
#pragma unroll
        for (int n = 0; n < 4; ++n) {
          float h1 = hb[row * 130 + colbase + n * 16];
          float h3 = acc[m][n][q];
          float gv = (h1 / (1.f + __expf(-h1))) * h3;
          gp[n * 16] = f2bf(gv);
        }
      }
  }
}

// =====================================================================
// GEMM2: out += wt * (g @ w2), atomic f32 epilogue.
// =====================================================================
__global__ __launch_bounds__(512, 2) void gemm2_kernel(
    const unsigned short* __restrict__ g, const unsigned short* __restrict__ w2t,
    const int* __restrict__ tok_list, const float* __restrict__ tok_w,
    const int* __restrict__ counts, const int* __restrict__ offsets,
    float* __restrict__ out, int expert_fixed) {
  __shared__ __align__(16) char smem[131072];
  constexpr int NK = HDIM / 64;                 // 112

  int nwg = gridDim.x;
  int orig = blockIdx.x;
  int wg = (orig & 7) * (nwg >> 3) + (orig >> 3);
  int mt = wg & (MT - 1);
  int rem = wg >> 5;
  int nt = rem % NT2;
  int e = expert_fixed >= 0 ? expert_fixed : rem / NT2;

  int cnt = counts[e];
  int mbase = mt * 256;
  if (mbase >= cnt) return;
  int off = offsets[e];
  int gshift = expert_fixed >= 0 ? 0 : off;
  int nbase = nt * 256;
  int rows = cnt - mbase; if (rows > 256) rows = 256;
  const unsigned short* w2te = w2t + (expert_fixed >= 0 ? (size_t)0 : (size_t)e * DDIM * HDIM);

  int tid = threadIdx.x, lane = tid & 63, wid = tid >> 6;
  int wr = wid >> 2, wc = wid & 3;

  int r16 = lane >> 2;
  int csrc = (lane & 3) ^ ((lane >> 3) & 3);
  const char* asrc[2]; const char* bsrc[2];
#pragma unroll
  for (int j = 0; j < 2; ++j) {
    int r = wid * 32 + j * 16 + r16;
    int m = mbase + r; if (m > cnt - 1) m = cnt - 1;
    asrc[j] = (const char*)g + (size_t)(m + gshift) * (HDIM * 2) + csrc * 16;
    bsrc[j] = (const char*)w2te + (size_t)(nbase + r) * (HDIM * 2) + csrc * 16;
  }
  int rowA = (wr * 128 + (lane & 15)) * 64;
  int rowB = (wc * 64  + (lane & 15)) * 64;
  int ckr  = (((lane >> 4) ^ ((lane >> 1) & 3)) * 16);

  f32x4 zv = {0.f, 0.f, 0.f, 0.f};
  f32x4 acc[8][4];
#pragma unroll
  for (int m = 0; m < 8; ++m)
#pragma unroll
    for (int n = 0; n < 4; ++n) acc[m][n] = zv;

  auto STAGE = [&](int buf, int kt) {
    char* base = smem + buf * 65536;
    size_t ko = (size_t)kt * 128;
#pragma unroll
    for (int s = 0; s < 2; ++s)
#pragma unroll
      for (int j = 0; j < 2; ++j) {
        char* dA = base + s * 16384 + wid * 2048 + j * 1024;
        char* dB = base + 32768 + s * 16384 + wid * 2048 + j * 1024;
        gload_lds16(asrc[j] + ko + s * 64, dA);
        gload_lds16(bsrc[j] + ko + s * 64, dB);
      }
  };

  STAGE(0, 0);
  __syncthreads();
  int buf = 0;
  for (int kt = 0; kt < NK; ++kt) {
    if (kt + 1 < NK) STAGE(buf ^ 1, kt + 1);
    char* Ab = smem + buf * 65536;
    char* Bb = Ab + 32768;
#pragma unroll
    for (int ks = 0; ks < 2; ++ks) {
      bf16x8 af[8], bfr[4];
#pragma unroll
      for (int mi = 0; mi < 8; ++mi)
        af[mi] = *(const bf16x8*)(Ab + ks * 16384 + rowA + mi * 1024 + ckr);
#pragma unroll
      for (int ni = 0; ni < 4; ++ni)
        bfr[ni] = *(const bf16x8*)(Bb + ks * 16384 + rowB + ni * 1024 + ckr);
      __builtin_amdgcn_s_setprio(1);
#pragma unroll
      for (int ni = 0; ni < 4; ++ni)
#pragma unroll
        for (int mi = 0; mi < 8; ++mi) mfma16(acc[mi][ni], af[mi], bfr[ni]);
      __builtin_amdgcn_s_setprio(0);
    }
    __syncthreads();
    buf ^= 1;
  }

#pragma unroll
  for (int m = 0; m < 8; ++m)
#pragma unroll
    for (int q = 0; q < 4; ++q) {
      int row = wr * 128 + m * 16 + (lane >> 4) * 4 + q;
      if (row >= rows) continue;
      int mi = mbase + row;
      int tok = tok_list[off + mi];
      float wt = tok_w[off + mi];
      float* op = out + (size_t)tok * DDIM + nbase + wc * 64 + (lane & 15);
#pragma unroll
      for (int n = 0; n < 4; ++n)
        atomicAdd(op + n * 16, acc[m][n][q] * wt);
    }
}

extern "C" void kernel_launch(void* const* d_in, const int* in_sizes, int n_in,
                              void* d_out, int out_size, void* d_ws, size_t ws_size,
                              hipStream_t stream) {
  const float* x      = (const float*)d_in[0];
  const float* gate_w = (const float*)d_in[1];
  const float* w1     = (const float*)d_in[2];
  const float* w2     = (const float*)d_in[3];
  const float* w3     = (const float*)d_in[4];
  float* out = (float*)d_out;
  char* ws = (char*)d_ws;

  size_t o = 0;
  int* counts  = (int*)(ws + o);
  int* offsets = counts + 8;
  int* cursor  = counts + 16;
  o += 256;
  int*   route_e = (int*)(ws + o);   o += (size_t)TT * 2 * 4;
  float* route_w = (float*)(ws + o); o += (size_t)TT * 2 * 4;
  int*   tok_list = (int*)(ws + o);  o += (size_t)TT * 2 * 4;
  float* tok_w = (float*)(ws + o);   o += (size_t)TT * 2 * 4;
  unsigned short* xbf = (unsigned short*)(ws + o); o += (size_t)TT * DDIM * 2;
  size_t fixed = o;

  const size_t WSZ = (size_t)HDIM * DDIM;
  const size_t wbf_full = (size_t)NEXP * WSZ * 2;
  const size_t gfull = (size_t)TT * 2 * HDIM * 2;

  hipMemsetAsync(counts, 0, 8 * sizeof(int), stream);
  hipMemsetAsync(out, 0, (size_t)TT * DDIM * sizeof(float), stream);
  cvt_bf16_kernel<<<4096, 256, 0, stream>>>(x, xbf, (long)TT * DDIM / 4);
  gate_kernel<<<TT, 256, 0, stream>>>(x, gate_w, route_e, route_w, counts);
  scan_kernel<<<1, 64, 0, stream>>>(counts, offsets, cursor);
  scatter_kernel<<<(TT + 255) / 256, 256, 0, stream>>>(route_e, route_w, cursor, tok_list, tok_w);

  if (ws_size >= fixed + 3 * wbf_full + gfull) {
    unsigned short* w1b = (unsigned short*)(ws + fixed);
    unsigned short* w3b = w1b + NEXP * WSZ;
    unsigned short* w2t = w3b + NEXP * WSZ;
    unsigned short* gbuf = w2t + NEXP * WSZ;
    cvt_bf16_kernel<<<8192, 256, 0, stream>>>(w1, w1b, (long)(NEXP * WSZ / 4));
    cvt_bf16_kernel<<<8192, 256, 0, stream>>>(w3, w3b, (long)(NEXP * WSZ / 4));
    transpose_w2_kernel<<<dim3(HDIM / 64, DDIM / 64, NEXP), 256, 0, stream>>>(w2, w2t, -1);
    gemm1_kernel<<<MT * NT1 * NEXP, 512, 0, stream>>>(
        xbf, w1b, w3b, tok_list, counts, offsets, gbuf, -1);
    gemm2_kernel<<<MT * NT2 * NEXP, 512, 0, stream>>>(
        gbuf, w2t, tok_list, tok_w, counts, offsets, out, -1);
  } else {
    unsigned short* w1b = (unsigned short*)(ws + fixed);
    unsigned short* w3b = w1b + WSZ;
    unsigned short* w2t = w3b + WSZ;
    unsigned short* gbuf = w2t + WSZ;
    for (int e = 0; e < NEXP; ++e) {
      cvt_bf16_kernel<<<4096, 256, 0, stream>>>(w1 + (size_t)e * WSZ, w1b, (long)(WSZ / 4));
      cvt_bf16_kernel<<<4096, 256, 0, stream>>>(w3 + (size_t)e * WSZ, w3b, (long)(WSZ / 4));
      transpose_w2_kernel<<<dim3(HDIM / 64, DDIM / 64, 1), 256, 0, stream>>>(w2, w2t, e);
      gemm1_kernel<<<MT * NT1, 512, 0, stream>>>(
          xbf, w1b, w3b, tok_list, counts, offsets, gbuf, e);
      gemm2_kernel<<<MT * NT2, 512, 0, stream>>>(
          gbuf, w2t, tok_list, tok_w, counts, offsets, out, e);
    }
  }
}

// Round 5
// 2494.906 us; speedup vs baseline: 1.1112x; 1.1112x over previous
//
#include <hip/hip_runtime.h>

#define TT   8192
#define DDIM 2048
#define HDIM 7168
#define NEXP 8
#define MT   32                 // max M-tiles per expert (8192/256)
#define NT1  (HDIM / 128)       // 56 n-tiles for gemm1 (128 h1 + 128 h3 cols each)
#define NT2  (DDIM / 256)       // 8 n-tiles for gemm2

typedef __attribute__((ext_vector_type(8))) short bf16x8;
typedef __attribute__((ext_vector_type(4))) short short4v;
typedef __attribute__((ext_vector_type(4))) float f32x4;

__device__ __forceinline__ unsigned short f2bf(float f) {
  unsigned int u = __builtin_bit_cast(unsigned int, f);
  u += 0x7fffu + ((u >> 16) & 1u);   // RNE
  return (unsigned short)(u >> 16);
}

__device__ __forceinline__ void gload_lds16(const void* gp, void* lp) {
  __builtin_amdgcn_global_load_lds((__attribute__((address_space(1))) void*)gp,
                                   (__attribute__((address_space(3))) void*)lp,
                                   16, 0, 0);
}

__device__ __forceinline__ void mfma16(f32x4& c, bf16x8 a, bf16x8 b) {
  asm("v_mfma_f32_16x16x32_bf16 %0, %1, %2, %0" : "+v"(c) : "v"(a), "v"(b));
}

__device__ __forceinline__ void wg_barrier() {
  asm volatile("" ::: "memory");
  __builtin_amdgcn_s_barrier();
  asm volatile("" ::: "memory");
}

// ---- 8-phase schedule building blocks (m201 template port) ----
// LDS per buffer (64KB): A_k0 | A_k1 | B_k0 | B_k1, each [256 rows][32 k] bf16
// (row stride 64B, XOR-swizzled 16B chunks; layout identical to round-4-verified).
// buf0 at 0, buf1 at 65536. Two barriers per phase => a stage issued in phase p
// can only land after phase p-1's readers retired (race-free by construction).
// vmcnt(6) at phases 4 and 8 only: 3 half-tiles (2 loads each) stay in flight.
#define PH(H, BA, BB, RDB, STG, SRCP, SOFF, VM)                              \
  do {                                                                       \
    if (RDB) {                                                               \
      _Pragma("unroll")                                                      \
      for (int n = 0; n < 4; ++n)                                            \
        bfr[n] = *(const bf16x8*)(smem + (BB) + rB + n * 1024);              \
    }                                                                        \
    _Pragma("unroll")                                                        \
    for (int m = 0; m < 4; ++m)                                              \
      af[m] = *(const bf16x8*)(smem + (BA) + rA + ((H) + m) * 1024);         \
    if ((STG) >= 0) {                                                        \
      gload_lds16(SRCP[0] + (SOFF), smem + (STG) + wid * 2048);              \
      gload_lds16(SRCP[1] + (SOFF), smem + (STG) + wid * 2048 + 1024);       \
    }                                                                        \
    wg_barrier();                                                            \
    asm volatile("s_waitcnt lgkmcnt(0)" ::: "memory");                       \
    __builtin_amdgcn_s_setprio(1);                                           \
    _Pragma("unroll")                                                        \
    for (int n = 0; n < 4; ++n) {                                            \
      _Pragma("unroll")                                                      \
      for (int m = 0; m < 4; ++m)                                            \
        mfma16(acc[(H) + m][n], af[m], bfr[n]);                              \
    }                                                                        \
    __builtin_amdgcn_s_setprio(0);                                           \
    if ((VM) == 6) asm volatile("s_waitcnt vmcnt(6)" ::: "memory");          \
    if ((VM) == 0) asm volatile("s_waitcnt vmcnt(0)" ::: "memory");          \
    wg_barrier();                                                            \
  } while (0)

// Full iteration i (tiles t=2i in buf0, t+1 in buf1); kb = i*256 bytes.
// Stage targets: p1->buf1.A_k1(t+1), p2->buf0.B_k0(t+2), p3->buf0.A_k0(t+2),
// p4->buf0.B_k1(t+2)+vm6, p5->buf0.A_k1(t+2), p6->buf1.B_k0(t+3),
// p7->buf1.A_k0(t+3), p8->buf1.B_k1(t+3)+vm6.
#define ITER_FULL(kb)                                                        \
  PH(0, 0,     32768,  1, 81920,  asrc, (kb) + 192, -1);                     \
  PH(4, 0,     32768,  0, 32768,  bsrc, (kb) + 256, -1);                     \
  PH(0, 16384, 49152,  1, 0,      asrc, (kb) + 256, -1);                     \
  PH(4, 16384, 49152,  0, 49152,  bsrc, (kb) + 320,  6);                     \
  PH(0, 65536, 98304,  1, 16384,  asrc, (kb) + 320, -1);                     \
  PH(4, 65536, 98304,  0, 98304,  bsrc, (kb) + 384, -1);                     \
  PH(0, 81920, 114688, 1, 65536,  asrc, (kb) + 384, -1);                     \
  PH(4, 81920, 114688, 0, 114688, bsrc, (kb) + 448,  6);

// Last iteration: only p1 stages (A_k1 of final tile); vmcnt(0) at p4 drains.
#define ITER_LAST(kb)                                                        \
  PH(0, 0,     32768,  1, 81920,  asrc, (kb) + 192, -1);                     \
  PH(4, 0,     32768,  0, -1,     asrc, 0,          -1);                     \
  PH(0, 16384, 49152,  1, -1,     asrc, 0,          -1);                     \
  PH(4, 16384, 49152,  0, -1,     asrc, 0,           0);                     \
  PH(0, 65536, 98304,  1, -1,     asrc, 0,          -1);                     \
  PH(4, 65536, 98304,  0, -1,     asrc, 0,          -1);                     \
  PH(0, 81920, 114688, 1, -1,     asrc, 0,          -1);                     \
  PH(4, 81920, 114688, 0, -1,     asrc, 0,          -1);

// Prologue: tile0's 4 half-tiles then 3 half-tiles of tile1, in exact issue
// order; vmcnt(6) forces the oldest 8 loads (= all of tile 0) retired.
#define PROLOGUE()                                                           \
  do {                                                                       \
    gload_lds16(asrc[0] + 0,   smem + 0      + wid * 2048);                  \
    gload_lds16(asrc[1] + 0,   smem + 0      + wid * 2048 + 1024);           \
    gload_lds16(bsrc[0] + 0,   smem + 32768  + wid * 2048);                  \
    gload_lds16(bsrc[1] + 0,   smem + 32768  + wid * 2048 + 1024);           \
    gload_lds16(asrc[0] + 64,  smem + 16384  + wid * 2048);                  \
    gload_lds16(asrc[1] + 64,  smem + 16384  + wid * 2048 + 1024);           \
    gload_lds16(bsrc[0] + 64,  smem + 49152  + wid * 2048);                  \
    gload_lds16(bsrc[1] + 64,  smem + 49152  + wid * 2048 + 1024);           \
    gload_lds16(bsrc[0] + 128, smem + 98304  + wid * 2048);                  \
    gload_lds16(bsrc[1] + 128, smem + 98304  + wid * 2048 + 1024);           \
    gload_lds16(asrc[0] + 128, smem + 65536  + wid * 2048);                  \
    gload_lds16(asrc[1] + 128, smem + 65536  + wid * 2048 + 1024);           \
    gload_lds16(bsrc[0] + 192, smem + 114688 + wid * 2048);                  \
    gload_lds16(bsrc[1] + 192, smem + 114688 + wid * 2048 + 1024);           \
    asm volatile("s_waitcnt vmcnt(6)" ::: "memory");                         \
    wg_barrier();                                                            \
  } while (0)

// ---------------- fp32 -> bf16 elementwise ----------------
__global__ __launch_bounds__(256) void cvt_bf16_kernel(const float* __restrict__ src,
                                                       unsigned short* __restrict__ dst,
                                                       long n4) {
  long i = (long)blockIdx.x * 256 + threadIdx.x;
  long stride = (long)gridDim.x * 256;
  for (; i < n4; i += stride) {
    float4 v = ((const float4*)src)[i];
    short4v s;
    s[0] = (short)f2bf(v.x); s[1] = (short)f2bf(v.y);
    s[2] = (short)f2bf(v.z); s[3] = (short)f2bf(v.w);
    ((short4v*)dst)[i] = s;
  }
}

// ---------------- gate ----------------
__global__ __launch_bounds__(256) void gate_kernel(const float* __restrict__ x,
                                                   const float* __restrict__ gw,
                                                   int* __restrict__ route_e,
                                                   float* __restrict__ route_w,
                                                   int* __restrict__ counts) {
  int t = blockIdx.x;
  int tid = threadIdx.x;
  const float* xr = x + (size_t)t * DDIM;
  float p[NEXP];
#pragma unroll
  for (int e = 0; e < NEXP; ++e) p[e] = 0.f;
#pragma unroll
  for (int c = 0; c < DDIM / (256 * 4); ++c) {
    int d = (c * 256 + tid) * 4;
    float4 xv = *(const float4*)(xr + d);
#pragma unroll
    for (int e = 0; e < NEXP; ++e) {
      float4 wv = *(const float4*)(gw + (size_t)e * DDIM + d);
      p[e] += xv.x * wv.x + xv.y * wv.y + xv.z * wv.z + xv.w * wv.w;
    }
  }
  __shared__ float red[NEXP][4];
  int lane = tid & 63, wid = tid >> 6;
#pragma unroll
  for (int e = 0; e < NEXP; ++e) {
    float v = p[e];
    for (int o = 32; o > 0; o >>= 1) v += __shfl_down(v, o);
    if (lane == 0) red[e][wid] = v;
  }
  __syncthreads();
  if (tid == 0) {
    float lg[NEXP];
#pragma unroll
    for (int e = 0; e < NEXP; ++e) lg[e] = red[e][0] + red[e][1] + red[e][2] + red[e][3];
    int i0 = 0;
#pragma unroll
    for (int e = 1; e < NEXP; ++e) if (lg[e] > lg[i0]) i0 = e;
    int i1 = -1;
#pragma unroll
    for (int e = 0; e < NEXP; ++e) {
      if (e == i0) continue;
      if (i1 < 0 || lg[e] > lg[i1]) i1 = e;
    }
    float w0 = 1.f / (1.f + __expf(lg[i1] - lg[i0]));
    float w1 = 1.f - w0;
    route_e[t * 2 + 0] = i0;  route_e[t * 2 + 1] = i1;
    route_w[t * 2 + 0] = w0;  route_w[t * 2 + 1] = w1;
    atomicAdd(&counts[i0], 1);
    atomicAdd(&counts[i1], 1);
  }
}

__global__ void scan_kernel(const int* __restrict__ counts, int* __restrict__ offsets,
                            int* __restrict__ cursor) {
  if (threadIdx.x == 0 && blockIdx.x == 0) {
    int o = 0;
    for (int e = 0; e < NEXP; ++e) { offsets[e] = o; cursor[e] = o; o += counts[e]; }
  }
}

__global__ __launch_bounds__(256) void scatter_kernel(const int* __restrict__ route_e,
                                                      const float* __restrict__ route_w,
                                                      int* __restrict__ cursor,
                                                      int* __restrict__ tok_list,
                                                      float* __restrict__ tok_w) {
  int t = blockIdx.x * 256 + threadIdx.x;
  if (t >= TT) return;
#pragma unroll
  for (int s = 0; s < 2; ++s) {
    int e = route_e[t * 2 + s];
    int p = atomicAdd(&cursor[e], 1);
    tok_list[p] = t;
    tok_w[p] = route_w[t * 2 + s];
  }
}

// ---------------- w2 [H,D] fp32 -> w2t [D,H] bf16 ----------------
__global__ __launch_bounds__(256) void transpose_w2_kernel(const float* __restrict__ w2,
                                                           unsigned short* __restrict__ w2t,
                                                           int expert_fixed) {
  int e = expert_fixed >= 0 ? expert_fixed : (int)blockIdx.z;
  const float* src = w2 + (size_t)e * HDIM * DDIM;
  unsigned short* dst = w2t + (expert_fixed >= 0 ? (size_t)0 : (size_t)e * DDIM * HDIM);
  int h0 = blockIdx.x * 64, d0 = blockIdx.y * 64;
  __shared__ __align__(8) unsigned short tile[64 * 66];
  int tid = threadIdx.x;
  int hr = tid >> 2;
#pragma unroll
  for (int j = 0; j < 4; ++j) {
    int f4 = (tid & 3) + j * 4;
    float4 v = *(const float4*)(src + (size_t)(h0 + hr) * DDIM + d0 + f4 * 4);
    unsigned int lo = (unsigned int)f2bf(v.x) | ((unsigned int)f2bf(v.y) << 16);
    unsigned int hi = (unsigned int)f2bf(v.z) | ((unsigned int)f2bf(v.w) << 16);
    char* bp = (char*)tile + hr * 132 + f4 * 8;
    *(unsigned int*)bp = lo;
    *(unsigned int*)(bp + 4) = hi;
  }
  __syncthreads();
  int dr = tid >> 2;
  int hbase = (tid & 3) * 16;
  unsigned short vals[16];
#pragma unroll
  for (int i = 0; i < 16; ++i)
    vals[i] = *(unsigned short*)((char*)tile + (hbase + i) * 132 + dr * 2);
  unsigned short* op = dst + (size_t)(d0 + dr) * HDIM + h0 + hbase;
#pragma unroll
  for (int j = 0; j < 4; ++j) {
    short4v s;
    s[0] = (short)vals[j * 4 + 0]; s[1] = (short)vals[j * 4 + 1];
    s[2] = (short)vals[j * 4 + 2]; s[3] = (short)vals[j * 4 + 3];
    *(short4v*)(op + j * 4) = s;
  }
}

// =====================================================================
// GEMM1: g = silu(Xe w1^T) * (Xe w3^T); 256x256 tile (128 w1 + 128 w3
// cols), BK=64, 8 waves, m201 8-phase counted-vmcnt schedule.
// =====================================================================
__global__ __launch_bounds__(512, 2) void gemm1_kernel(
    const unsigned short* __restrict__ xbf, const unsigned short* __restrict__ w1b,
    const unsigned short* __restrict__ w3b, const int* __restrict__ tok_list,
    const int* __restrict__ counts, const int* __restrict__ offsets,
    unsigned short* __restrict__ g, int expert_fixed) {
  __shared__ __align__(16) char smem[133120];   // 128KB staging + epi hb[256][130] f32
  constexpr int NI = DDIM / 128;                // 16 iterations (2 K-tiles each)

  int nwg = gridDim.x;
  int orig = blockIdx.x;
  int wg = (orig & 7) * (nwg >> 3) + (orig >> 3);   // bijective XCD swizzle (nwg%8==0)
  int mt = wg & (MT - 1);
  int rem = wg >> 5;
  int nt = rem % NT1;
  int e = expert_fixed >= 0 ? expert_fixed : rem / NT1;

  int cnt = counts[e];
  int mbase = mt * 256;
  if (mbase >= cnt) return;
  int off = offsets[e];
  int gshift = expert_fixed >= 0 ? 0 : off;
  int rows = cnt - mbase; if (rows > 256) rows = 256;

  const unsigned short* w1e = expert_fixed >= 0 ? w1b : w1b + (size_t)e * HDIM * DDIM;
  const unsigned short* w3e = expert_fixed >= 0 ? w3b : w3b + (size_t)e * HDIM * DDIM;

  int tid = threadIdx.x, lane = tid & 63, wid = tid >> 6;
  int wr = wid >> 2, wc = wid & 3;

  // staging sources: per half-tile gload j, wave covers rows wid*32+j*16+(lane>>2)
  int r16 = lane >> 2;
  int csrc = (lane & 3) ^ ((lane >> 3) & 3);    // pre-swizzled source chunk
  const char* asrc[2]; const char* bsrc[2];
#pragma unroll
  for (int j = 0; j < 2; ++j) {
    int r = wid * 32 + j * 16 + r16;
    int m = mbase + r; if (m > cnt - 1) m = cnt - 1;
    int tok = tok_list[off + m];
    asrc[j] = (const char*)xbf + (size_t)tok * (DDIM * 2) + csrc * 16;
    const char* base = (r < 128)
        ? (const char*)w1e + (size_t)(nt * 128 + r) * (DDIM * 2)
        : (const char*)w3e + (size_t)(nt * 128 + r - 128) * (DDIM * 2);
    bsrc[j] = base + csrc * 16;
  }
  // fragment read offsets (lane-constant; layout identical to round 4)
  int rA = (wr * 128 + (lane & 15)) * 64 + (((lane >> 4) ^ ((lane >> 1) & 3)) * 16);
  int rB = (wc * 64  + (lane & 15)) * 64 + (((lane >> 4) ^ ((lane >> 1) & 3)) * 16);

  f32x4 zv = {0.f, 0.f, 0.f, 0.f};
  f32x4 acc[8][4];
#pragma unroll
  for (int m = 0; m < 8; ++m)
#pragma unroll
    for (int n = 0; n < 4; ++n) acc[m][n] = zv;
  bf16x8 af[4], bfr[4];

  PROLOGUE();
#pragma unroll 1
  for (int i = 0; i < NI - 1; ++i) {
    size_t kb = (size_t)i * 256;
    ITER_FULL(kb);
  }
  {
    size_t kb = (size_t)(NI - 1) * 256;
    ITER_LAST(kb);
  }

  // ---- epilogue: h1 (wc<2) -> LDS; h3 (wc>=2) computes g = silu(h1)*h3 ----
  float* hb = (float*)smem;                       // [256][130] f32
  if (wc < 2) {
#pragma unroll
    for (int m = 0; m < 8; ++m)
#pragma unroll
      for (int q = 0; q < 4; ++q) {
        int row = wr * 128 + m * 16 + (lane >> 4) * 4 + q;
        int col = wc * 64 + (lane & 15);
#pragma unroll
        for (int n = 0; n < 4; ++n)
          hb[row * 130 + col + n * 16] = acc[m][n][q];
      }
  }
  asm volatile("s_waitcnt lgkmcnt(0)" ::: "memory");
  wg_barrier();
  if (wc >= 2) {
#pragma unroll
    for (int m = 0; m < 8; ++m)
#pragma unroll
      for (int q = 0; q < 4; ++q) {
        int row = wr * 128 + m * 16 + (lane >> 4) * 4 + q;
        if (row >= rows) continue;
        size_t grow = (size_t)(mbase + row + gshift);
        int colbase = (wc - 2) * 64 + (lane & 15);
        unsigned short* gp = g + grow * HDIM + nt * 128 + colbase;
#pragma unroll
        for (int n = 0; n < 4; ++n) {
          float h1 = hb[row * 130 + colbase + n * 16];
          float h3 = acc[m][n][q];
          float gv = (h1 / (1.f + __expf(-h1))) * h3;
          gp[n * 16] = f2bf(gv);
        }
      }
  }
}

// =====================================================================
// GEMM2: out += wt * (g @ w2) via w2t, same 8-phase schedule, atomics.
// =====================================================================
__global__ __launch_bounds__(512, 2) void gemm2_kernel(
    const unsigned short* __restrict__ g, const unsigned short* __restrict__ w2t,
    const int* __restrict__ tok_list, const float* __restrict__ tok_w,
    const int* __restrict__ counts, const int* __restrict__ offsets,
    float* __restrict__ out, int expert_fixed) {
  __shared__ __align__(16) char smem[131072];
  constexpr int NI = HDIM / 128;                // 56 iterations

  int nwg = gridDim.x;
  int orig = blockIdx.x;
  int wg = (orig & 7) * (nwg >> 3) + (orig >> 3);
  int mt = wg & (MT - 1);
  int rem = wg >> 5;
  int nt = rem % NT2;
  int e = expert_fixed >= 0 ? expert_fixed : rem / NT2;

  int cnt = counts[e];
  int mbase = mt * 256;
  if (mbase >= cnt) return;
  int off = offsets[e];
  int gshift = expert_fixed >= 0 ? 0 : off;
  int nbase = nt * 256;
  int rows = cnt - mbase; if (rows > 256) rows = 256;
  const unsigned short* w2te = w2t + (expert_fixed >= 0 ? (size_t)0 : (size_t)e * DDIM * HDIM);

  int tid = threadIdx.x, lane = tid & 63, wid = tid >> 6;
  int wr = wid >> 2, wc = wid & 3;

  int r16 = lane >> 2;
  int csrc = (lane & 3) ^ ((lane >> 3) & 3);
  const char* asrc[2]; const char* bsrc[2];
#pragma unroll
  for (int j = 0; j < 2; ++j) {
    int r = wid * 32 + j * 16 + r16;
    int m = mbase + r; if (m > cnt - 1) m = cnt - 1;
    asrc[j] = (const char*)g + (size_t)(m + gshift) * (HDIM * 2) + csrc * 16;
    bsrc[j] = (const char*)w2te + (size_t)(nbase + r) * (HDIM * 2) + csrc * 16;
  }
  int rA = (wr * 128 + (lane & 15)) * 64 + (((lane >> 4) ^ ((lane >> 1) & 3)) * 16);
  int rB = (wc * 64  + (lane & 15)) * 64 + (((lane >> 4) ^ ((lane >> 1) & 3)) * 16);

  f32x4 zv = {0.f, 0.f, 0.f, 0.f};
  f32x4 acc[8][4];
#pragma unroll
  for (int m = 0; m < 8; ++m)
#pragma unroll
    for (int n = 0; n < 4; ++n) acc[m][n] = zv;
  bf16x8 af[4], bfr[4];

  PROLOGUE();
#pragma unroll 1
  for (int i = 0; i < NI - 1; ++i) {
    size_t kb = (size_t)i * 256;
    ITER_FULL(kb);
  }
  {
    size_t kb = (size_t)(NI - 1) * 256;
    ITER_LAST(kb);
  }

#pragma unroll
  for (int m = 0; m < 8; ++m)
#pragma unroll
    for (int q = 0; q < 4; ++q) {
      int row = wr * 128 + m * 16 + (lane >> 4) * 4 + q;
      if (row >= rows) continue;
      int mi = mbase + row;
      int tok = tok_list[off + mi];
      float wt = tok_w[off + mi];
      float* op = out + (size_t)tok * DDIM + nbase + wc * 64 + (lane & 15);
#pragma unroll
      for (int n = 0; n < 4; ++n)
        atomicAdd(op + n * 16, acc[m][n][q] * wt);
    }
}

extern "C" void kernel_launch(void* const* d_in, const int* in_sizes, int n_in,
                              void* d_out, int out_size, void* d_ws, size_t ws_size,
                              hipStream_t stream) {
  const float* x      = (const float*)d_in[0];
  const float* gate_w = (const float*)d_in[1];
  const float* w1     = (const float*)d_in[2];
  const float* w2     = (const float*)d_in[3];
  const float* w3     = (const float*)d_in[4];
  float* out = (float*)d_out;
  char* ws = (char*)d_ws;

  size_t o = 0;
  int* counts  = (int*)(ws + o);
  int* offsets = counts + 8;
  int* cursor  = counts + 16;
  o += 256;
  int*   route_e = (int*)(ws + o);   o += (size_t)TT * 2 * 4;
  float* route_w = (float*)(ws + o); o += (size_t)TT * 2 * 4;
  int*   tok_list = (int*)(ws + o);  o += (size_t)TT * 2 * 4;
  float* tok_w = (float*)(ws + o);   o += (size_t)TT * 2 * 4;
  unsigned short* xbf = (unsigned short*)(ws + o); o += (size_t)TT * DDIM * 2;
  size_t fixed = o;

  const size_t WSZ = (size_t)HDIM * DDIM;
  const size_t wbf_full = (size_t)NEXP * WSZ * 2;
  const size_t gfull = (size_t)TT * 2 * HDIM * 2;

  hipMemsetAsync(counts, 0, 8 * sizeof(int), stream);
  hipMemsetAsync(out, 0, (size_t)TT * DDIM * sizeof(float), stream);
  cvt_bf16_kernel<<<4096, 256, 0, stream>>>(x, xbf, (long)TT * DDIM / 4);
  gate_kernel<<<TT, 256, 0, stream>>>(x, gate_w, route_e, route_w, counts);
  scan_kernel<<<1, 64, 0, stream>>>(counts, offsets, cursor);
  scatter_kernel<<<(TT + 255) / 256, 256, 0, stream>>>(route_e, route_w, cursor, tok_list, tok_w);

  if (ws_size >= fixed + 3 * wbf_full + gfull) {
    unsigned short* w1b = (unsigned short*)(ws + fixed);
    unsigned short* w3b = w1b + NEXP * WSZ;
    unsigned short* w2t = w3b + NEXP * WSZ;
    unsigned short* gbuf = w2t + NEXP * WSZ;
    cvt_bf16_kernel<<<8192, 256, 0, stream>>>(w1, w1b, (long)(NEXP * WSZ / 4));
    cvt_bf16_kernel<<<8192, 256, 0, stream>>>(w3, w3b, (long)(NEXP * WSZ / 4));
    transpose_w2_kernel<<<dim3(HDIM / 64, DDIM / 64, NEXP), 256, 0, stream>>>(w2, w2t, -1);
    gemm1_kernel<<<MT * NT1 * NEXP, 512, 0, stream>>>(
        xbf, w1b, w3b, tok_list, counts, offsets, gbuf, -1);
    gemm2_kernel<<<MT * NT2 * NEXP, 512, 0, stream>>>(
        gbuf, w2t, tok_list, tok_w, counts, offsets, out, -1);
  } else {
    unsigned short* w1b = (unsigned short*)(ws + fixed);
    unsigned short* w3b = w1b + WSZ;
    unsigned short* w2t = w3b + WSZ;
    unsigned short* gbuf = w2t + WSZ;
    for (int e = 0; e < NEXP; ++e) {
      cvt_bf16_kernel<<<4096, 256, 0, stream>>>(w1 + (size_t)e * WSZ, w1b, (long)(WSZ / 4));
      cvt_bf16_kernel<<<4096, 256, 0, stream>>>(w3 + (size_t)e * WSZ, w3b, (long)(WSZ / 4));
      transpose_w2_kernel<<<dim3(HDIM / 64, DDIM / 64, 1), 256, 0, stream>>>(w2, w2t, e);
      gemm1_kernel<<<MT * NT1, 512, 0, stream>>>(
          xbf, w1b, w3b, tok_list, counts, offsets, gbuf, e);
      gemm2_kernel<<<MT * NT2, 512, 0, stream>>>(
          gbuf, w2t, tok_list, tok_w, counts, offsets, out, e);
    }
  }
}

// Round 6
// 2490.686 us; speedup vs baseline: 1.1131x; 1.0017x over previous
//
#include <hip/hip_runtime.h>

#define TT   8192
#define DDIM 2048
#define HDIM 7168
#define NEXP 8
#define MT   32                 // max M-tiles per expert (8192/256)
#define NT1  (HDIM / 128)       // 56 n-tiles for gemm1 (128 h1 + 128 h3 cols each)
#define NT2  (DDIM / 256)       // 8 n-tiles for gemm2

typedef __attribute__((ext_vector_type(8))) short bf16x8;
typedef __attribute__((ext_vector_type(4))) short short4v;
typedef __attribute__((ext_vector_type(4))) float f32x4;

__device__ __forceinline__ unsigned short f2bf(float f) {
  unsigned int u = __builtin_bit_cast(unsigned int, f);
  u += 0x7fffu + ((u >> 16) & 1u);   // RNE
  return (unsigned short)(u >> 16);
}

__device__ __forceinline__ void gload_lds16(const void* gp, void* lp) {
  __builtin_amdgcn_global_load_lds((__attribute__((address_space(1))) void*)gp,
                                   (__attribute__((address_space(3))) void*)lp,
                                   16, 0, 0);
}

// Builtin (not inline asm): lets the compiler keep acc in AGPRs natively.
// Round-5 asm "+v" forced v_accvgpr_read/write shuttles around every MFMA
// (VGPR_Count=112 with 128-reg acc proved acc lived in AGPRs).
__device__ __forceinline__ void mfma16(f32x4& c, bf16x8 a, bf16x8 b) {
  c = __builtin_amdgcn_mfma_f32_16x16x32_bf16(a, b, c, 0, 0, 0);
}

__device__ __forceinline__ void wg_barrier() {
  asm volatile("" ::: "memory");
  __builtin_amdgcn_s_barrier();
  asm volatile("" ::: "memory");
}

// ---- 8-phase schedule building blocks (m201 template port) ----
// LDS per buffer (64KB): A_k0 | A_k1 | B_k0 | B_k1, each [256 rows][32 k] bf16
// (row stride 64B, XOR-swizzled 16B chunks).  buf0 at 0, buf1 at 65536.
// Two barriers per phase => a stage issued in phase p can only land after
// phase p-1's readers retired (lgkmcnt(0) before barrier-2 makes barrier-2 a
// "reads retired" checkpoint).  vmcnt(6) at phases 4/8 only (2 loads x 3
// half-tiles in flight).  sched_barrier(0) after lgkmcnt: rule #18 (builtin
// MFMA is register-only and may otherwise hoist past the inline-asm wait).
#define PH(H, BA, BB, RDB, STG, SRCP, SOFF, VM)                              \
  do {                                                                       \
    if (RDB) {                                                               \
      _Pragma("unroll")                                                      \
      for (int n = 0; n < 4; ++n)                                            \
        bfr[n] = *(const bf16x8*)(smem + (BB) + rB + n * 1024);              \
    }                                                                        \
    _Pragma("unroll")                                                        \
    for (int m = 0; m < 4; ++m)                                              \
      af[m] = *(const bf16x8*)(smem + (BA) + rA + ((H) + m) * 1024);         \
    if ((STG) >= 0) {                                                        \
      gload_lds16(SRCP[0] + (SOFF), smem + (STG) + wid * 2048);              \
      gload_lds16(SRCP[1] + (SOFF), smem + (STG) + wid * 2048 + 1024);       \
    }                                                                        \
    wg_barrier();                                                            \
    asm volatile("s_waitcnt lgkmcnt(0)" ::: "memory");                       \
    __builtin_amdgcn_sched_barrier(0);                                       \
    __builtin_amdgcn_s_setprio(1);                                           \
    _Pragma("unroll")                                                        \
    for (int n = 0; n < 4; ++n) {                                            \
      _Pragma("unroll")                                                      \
      for (int m = 0; m < 4; ++m)                                            \
        mfma16(acc[(H) + m][n], af[m], bfr[n]);                              \
    }                                                                        \
    __builtin_amdgcn_s_setprio(0);                                           \
    if ((VM) == 6) asm volatile("s_waitcnt vmcnt(6)" ::: "memory");          \
    if ((VM) == 0) asm volatile("s_waitcnt vmcnt(0)" ::: "memory");          \
    wg_barrier();                                                            \
  } while (0)

// Full iteration i (tiles t=2i in buf0, t+1 in buf1); kb = i*256 bytes.
// Stage targets: p1->buf1.A_k1(t+1), p2->buf0.B_k0(t+2), p3->buf0.A_k0(t+2),
// p4->buf0.B_k1(t+2)+vm6, p5->buf0.A_k1(t+2), p6->buf1.B_k0(t+3),
// p7->buf1.A_k0(t+3), p8->buf1.B_k1(t+3)+vm6.   (Ledger verified r5.)
#define ITER_FULL(kb)                                                        \
  PH(0, 0,     32768,  1, 81920,  asrc, (kb) + 192, -1);                     \
  PH(4, 0,     32768,  0, 32768,  bsrc, (kb) + 256, -1);                     \
  PH(0, 16384, 49152,  1, 0,      asrc, (kb) + 256, -1);                     \
  PH(4, 16384, 49152,  0, 49152,  bsrc, (kb) + 320,  6);                     \
  PH(0, 65536, 98304,  1, 16384,  asrc, (kb) + 320, -1);                     \
  PH(4, 65536, 98304,  0, 98304,  bsrc, (kb) + 384, -1);                     \
  PH(0, 81920, 114688, 1, 65536,  asrc, (kb) + 384, -1);                     \
  PH(4, 81920, 114688, 0, 114688, bsrc, (kb) + 448,  6);

// Last iteration: only p1 stages (A_k1 of final tile); vmcnt(0) at p4 drains.
#define ITER_LAST(kb)                                                        \
  PH(0, 0,     32768,  1, 81920,  asrc, (kb) + 192, -1);                     \
  PH(4, 0,     32768,  0, -1,     asrc, 0,          -1);                     \
  PH(0, 16384, 49152,  1, -1,     asrc, 0,          -1);                     \
  PH(4, 16384, 49152,  0, -1,     asrc, 0,           0);                     \
  PH(0, 65536, 98304,  1, -1,     asrc, 0,          -1);                     \
  PH(4, 65536, 98304,  0, -1,     asrc, 0,          -1);                     \
  PH(0, 81920, 114688, 1, -1,     asrc, 0,          -1);                     \
  PH(4, 81920, 114688, 0, -1,     asrc, 0,          -1);

// Prologue: tile0's 4 half-tiles then 3 half-tiles of tile1, in exact issue
// order; vmcnt(6) forces the oldest 8 loads (= all of tile 0) retired.
#define PROLOGUE()                                                           \
  do {                                                                       \
    gload_lds16(asrc[0] + 0,   smem + 0      + wid * 2048);                  \
    gload_lds16(asrc[1] + 0,   smem + 0      + wid * 2048 + 1024);           \
    gload_lds16(bsrc[0] + 0,   smem + 32768  + wid * 2048);                  \
    gload_lds16(bsrc[1] + 0,   smem + 32768  + wid * 2048 + 1024);           \
    gload_lds16(asrc[0] + 64,  smem + 16384  + wid * 2048);                  \
    gload_lds16(asrc[1] + 64,  smem + 16384  + wid * 2048 + 1024);           \
    gload_lds16(bsrc[0] + 64,  smem + 49152  + wid * 2048);                  \
    gload_lds16(bsrc[1] + 64,  smem + 49152  + wid * 2048 + 1024);           \
    gload_lds16(bsrc[0] + 128, smem + 98304  + wid * 2048);                  \
    gload_lds16(bsrc[1] + 128, smem + 98304  + wid * 2048 + 1024);           \
    gload_lds16(asrc[0] + 128, smem + 65536  + wid * 2048);                  \
    gload_lds16(asrc[1] + 128, smem + 65536  + wid * 2048 + 1024);           \
    gload_lds16(bsrc[0] + 192, smem + 114688 + wid * 2048);                  \
    gload_lds16(bsrc[1] + 192, smem + 114688 + wid * 2048 + 1024);           \
    asm volatile("s_waitcnt vmcnt(6)" ::: "memory");                         \
    wg_barrier();                                                            \
  } while (0)

// ---------------- fp32 -> bf16 elementwise ----------------
__global__ __launch_bounds__(256) void cvt_bf16_kernel(const float* __restrict__ src,
                                                       unsigned short* __restrict__ dst,
                                                       long n4) {
  long i = (long)blockIdx.x * 256 + threadIdx.x;
  long stride = (long)gridDim.x * 256;
  for (; i < n4; i += stride) {
    float4 v = ((const float4*)src)[i];
    short4v s;
    s[0] = (short)f2bf(v.x); s[1] = (short)f2bf(v.y);
    s[2] = (short)f2bf(v.z); s[3] = (short)f2bf(v.w);
    ((short4v*)dst)[i] = s;
  }
}

// ---------------- gate ----------------
__global__ __launch_bounds__(256) void gate_kernel(const float* __restrict__ x,
                                                   const float* __restrict__ gw,
                                                   int* __restrict__ route_e,
                                                   float* __restrict__ route_w,
                                                   int* __restrict__ counts) {
  int t = blockIdx.x;
  int tid = threadIdx.x;
  const float* xr = x + (size_t)t * DDIM;
  float p[NEXP];
#pragma unroll
  for (int e = 0; e < NEXP; ++e) p[e] = 0.f;
#pragma unroll
  for (int c = 0; c < DDIM / (256 * 4); ++c) {
    int d = (c * 256 + tid) * 4;
    float4 xv = *(const float4*)(xr + d);
#pragma unroll
    for (int e = 0; e < NEXP; ++e) {
      float4 wv = *(const float4*)(gw + (size_t)e * DDIM + d);
      p[e] += xv.x * wv.x + xv.y * wv.y + xv.z * wv.z + xv.w * wv.w;
    }
  }
  __shared__ float red[NEXP][4];
  int lane = tid & 63, wid = tid >> 6;
#pragma unroll
  for (int e = 0; e < NEXP; ++e) {
    float v = p[e];
    for (int o = 32; o > 0; o >>= 1) v += __shfl_down(v, o);
    if (lane == 0) red[e][wid] = v;
  }
  __syncthreads();
  if (tid == 0) {
    float lg[NEXP];
#pragma unroll
    for (int e = 0; e < NEXP; ++e) lg[e] = red[e][0] + red[e][1] + red[e][2] + red[e][3];
    int i0 = 0;
#pragma unroll
    for (int e = 1; e < NEXP; ++e) if (lg[e] > lg[i0]) i0 = e;
    int i1 = -1;
#pragma unroll
    for (int e = 0; e < NEXP; ++e) {
      if (e == i0) continue;
      if (i1 < 0 || lg[e] > lg[i1]) i1 = e;
    }
    float w0 = 1.f / (1.f + __expf(lg[i1] - lg[i0]));
    float w1 = 1.f - w0;
    route_e[t * 2 + 0] = i0;  route_e[t * 2 + 1] = i1;
    route_w[t * 2 + 0] = w0;  route_w[t * 2 + 1] = w1;
    atomicAdd(&counts[i0], 1);
    atomicAdd(&counts[i1], 1);
  }
}

__global__ void scan_kernel(const int* __restrict__ counts, int* __restrict__ offsets,
                            int* __restrict__ cursor) {
  if (threadIdx.x == 0 && blockIdx.x == 0) {
    int o = 0;
    for (int e = 0; e < NEXP; ++e) { offsets[e] = o; cursor[e] = o; o += counts[e]; }
  }
}

__global__ __launch_bounds__(256) void scatter_kernel(const int* __restrict__ route_e,
                                                      const float* __restrict__ route_w,
                                                      int* __restrict__ cursor,
                                                      int* __restrict__ tok_list,
                                                      float* __restrict__ tok_w) {
  int t = blockIdx.x * 256 + threadIdx.x;
  if (t >= TT) return;
#pragma unroll
  for (int s = 0; s < 2; ++s) {
    int e = route_e[t * 2 + s];
    int p = atomicAdd(&cursor[e], 1);
    tok_list[p] = t;
    tok_w[p] = route_w[t * 2 + s];
  }
}

// ---------------- w2 [H,D] fp32 -> w2t [D,H] bf16 ----------------
__global__ __launch_bounds__(256) void transpose_w2_kernel(const float* __restrict__ w2,
                                                           unsigned short* __restrict__ w2t,
                                                           int expert_fixed) {
  int e = expert_fixed >= 0 ? expert_fixed : (int)blockIdx.z;
  const float* src = w2 + (size_t)e * HDIM * DDIM;
  unsigned short* dst = w2t + (expert_fixed >= 0 ? (size_t)0 : (size_t)e * DDIM * HDIM);
  int h0 = blockIdx.x * 64, d0 = blockIdx.y * 64;
  __shared__ __align__(8) unsigned short tile[64 * 66];
  int tid = threadIdx.x;
  int hr = tid >> 2;
#pragma unroll
  for (int j = 0; j < 4; ++j) {
    int f4 = (tid & 3) + j * 4;
    float4 v = *(const float4*)(src + (size_t)(h0 + hr) * DDIM + d0 + f4 * 4);
    unsigned int lo = (unsigned int)f2bf(v.x) | ((unsigned int)f2bf(v.y) << 16);
    unsigned int hi = (unsigned int)f2bf(v.z) | ((unsigned int)f2bf(v.w) << 16);
    char* bp = (char*)tile + hr * 132 + f4 * 8;
    *(unsigned int*)bp = lo;
    *(unsigned int*)(bp + 4) = hi;
  }
  __syncthreads();
  int dr = tid >> 2;
  int hbase = (tid & 3) * 16;
  unsigned short vals[16];
#pragma unroll
  for (int i = 0; i < 16; ++i)
    vals[i] = *(unsigned short*)((char*)tile + (hbase + i) * 132 + dr * 2);
  unsigned short* op = dst + (size_t)(d0 + dr) * HDIM + h0 + hbase;
#pragma unroll
  for (int j = 0; j < 4; ++j) {
    short4v s;
    s[0] = (short)vals[j * 4 + 0]; s[1] = (short)vals[j * 4 + 1];
    s[2] = (short)vals[j * 4 + 2]; s[3] = (short)vals[j * 4 + 3];
    *(short4v*)(op + j * 4) = s;
  }
}

// =====================================================================
// GEMM1: g = silu(Xe w1^T) * (Xe w3^T); 256x256 tile (128 w1 + 128 w3
// cols), BK=64, 8 waves, m201 8-phase counted-vmcnt schedule.
// =====================================================================
__global__ __launch_bounds__(512, 2) void gemm1_kernel(
    const unsigned short* __restrict__ xbf, const unsigned short* __restrict__ w1b,
    const unsigned short* __restrict__ w3b, const int* __restrict__ tok_list,
    const int* __restrict__ counts, const int* __restrict__ offsets,
    unsigned short* __restrict__ g, int expert_fixed) {
  __shared__ __align__(16) char smem[133120];   // 128KB staging + epi hb[256][130] f32
  constexpr int NI = DDIM / 128;                // 16 iterations (2 K-tiles each)

  int nwg = gridDim.x;
  int orig = blockIdx.x;
  int wg = (orig & 7) * (nwg >> 3) + (orig >> 3);   // bijective XCD swizzle (nwg%8==0)
  int mt = wg & (MT - 1);
  int rem = wg >> 5;
  int nt = rem % NT1;
  int e = expert_fixed >= 0 ? expert_fixed : rem / NT1;

  int cnt = counts[e];
  int mbase = mt * 256;
  if (mbase >= cnt) return;
  int off = offsets[e];
  int gshift = expert_fixed >= 0 ? 0 : off;
  int rows = cnt - mbase; if (rows > 256) rows = 256;

  const unsigned short* w1e = expert_fixed >= 0 ? w1b : w1b + (size_t)e * HDIM * DDIM;
  const unsigned short* w3e = expert_fixed >= 0 ? w3b : w3b + (size_t)e * HDIM * DDIM;

  int tid = threadIdx.x, lane = tid & 63, wid = tid >> 6;
  int wr = wid >> 2, wc = wid & 3;

  // staging sources: per half-tile gload j, wave covers rows wid*32+j*16+(lane>>2)
  int r16 = lane >> 2;
  int csrc = (lane & 3) ^ ((lane >> 3) & 3);    // pre-swizzled source chunk
  const char* asrc[2]; const char* bsrc[2];
#pragma unroll
  for (int j = 0; j < 2; ++j) {
    int r = wid * 32 + j * 16 + r16;
    int m = mbase + r; if (m > cnt - 1) m = cnt - 1;
    int tok = tok_list[off + m];
    asrc[j] = (const char*)xbf + (size_t)tok * (DDIM * 2) + csrc * 16;
    const char* base = (r < 128)
        ? (const char*)w1e + (size_t)(nt * 128 + r) * (DDIM * 2)
        : (const char*)w3e + (size_t)(nt * 128 + r - 128) * (DDIM * 2);
    bsrc[j] = base + csrc * 16;
  }
  // fragment read offsets (lane-constant)
  int rA = (wr * 128 + (lane & 15)) * 64 + (((lane >> 4) ^ ((lane >> 1) & 3)) * 16);
  int rB = (wc * 64  + (lane & 15)) * 64 + (((lane >> 4) ^ ((lane >> 1) & 3)) * 16);

  f32x4 zv = {0.f, 0.f, 0.f, 0.f};
  f32x4 acc[8][4];
#pragma unroll
  for (int m = 0; m < 8; ++m)
#pragma unroll
    for (int n = 0; n < 4; ++n) acc[m][n] = zv;
  bf16x8 af[4], bfr[4];

  PROLOGUE();
#pragma unroll 1
  for (int i = 0; i < NI - 1; ++i) {
    size_t kb = (size_t)i * 256;
    ITER_FULL(kb);
  }
  {
    size_t kb = (size_t)(NI - 1) * 256;
    ITER_LAST(kb);
  }

  // ---- epilogue: h1 (wc<2) -> LDS; h3 (wc>=2) computes g = silu(h1)*h3 ----
  float* hb = (float*)smem;                       // [256][130] f32
  if (wc < 2) {
#pragma unroll
    for (int m = 0; m < 8; ++m)
#pragma unroll
      for (int q = 0; q < 4; ++q) {
        int row = wr * 128 + m * 16 + (lane >> 4) * 4 + q;
        int col = wc * 64 + (lane & 15);
#pragma unroll
        for (int n = 0; n < 4; ++n)
          hb[row * 130 + col + n * 16] = acc[m][n][q];
      }
  }
  asm volatile("s_waitcnt lgkmcnt(0)" ::: "memory");
  wg_barrier();
  if (wc >= 2) {
#pragma unroll
    for (int m = 0; m < 8; ++m)
#pragma unroll
      for (int q = 0; q < 4; ++q) {
        int row = wr * 128 + m * 16 + (lane >> 4) * 4 + q;
        if (row >= rows) continue;
        size_t grow = (size_t)(mbase + row + gshift);
        int colbase = (wc - 2) * 64 + (lane & 15);
        unsigned short* gp = g + grow * HDIM + nt * 128 + colbase;
#pragma unroll
        for (int n = 0; n < 4; ++n) {
          float h1 = hb[row * 130 + colbase + n * 16];
          float h3 = acc[m][n][q];
          float gv = (h1 / (1.f + __expf(-h1))) * h3;
          gp[n * 16] = f2bf(gv);
        }
      }
  }
}

// =====================================================================
// GEMM2: out += wt * (g @ w2) via w2t, same 8-phase schedule, atomics.
// =====================================================================
__global__ __launch_bounds__(512, 2) void gemm2_kernel(
    const unsigned short* __restrict__ g, const unsigned short* __restrict__ w2t,
    const int* __restrict__ tok_list, const float* __restrict__ tok_w,
    const int* __restrict__ counts, const int* __restrict__ offsets,
    float* __restrict__ out, int expert_fixed) {
  __shared__ __align__(16) char smem[131072];
  constexpr int NI = HDIM / 128;                // 56 iterations

  int nwg = gridDim.x;
  int orig = blockIdx.x;
  int wg = (orig & 7) * (nwg >> 3) + (orig >> 3);
  int mt = wg & (MT - 1);
  int rem = wg >> 5;
  int nt = rem % NT2;
  int e = expert_fixed >= 0 ? expert_fixed : rem / NT2;

  int cnt = counts[e];
  int mbase = mt * 256;
  if (mbase >= cnt) return;
  int off = offsets[e];
  int gshift = expert_fixed >= 0 ? 0 : off;
  int nbase = nt * 256;
  int rows = cnt - mbase; if (rows > 256) rows = 256;
  const unsigned short* w2te = w2t + (expert_fixed >= 0 ? (size_t)0 : (size_t)e * DDIM * HDIM);

  int tid = threadIdx.x, lane = tid & 63, wid = tid >> 6;
  int wr = wid >> 2, wc = wid & 3;

  int r16 = lane >> 2;
  int csrc = (lane & 3) ^ ((lane >> 3) & 3);
  const char* asrc[2]; const char* bsrc[2];
#pragma unroll
  for (int j = 0; j < 2; ++j) {
    int r = wid * 32 + j * 16 + r16;
    int m = mbase + r; if (m > cnt - 1) m = cnt - 1;
    asrc[j] = (const char*)g + (size_t)(m + gshift) * (HDIM * 2) + csrc * 16;
    bsrc[j] = (const char*)w2te + (size_t)(nbase + r) * (HDIM * 2) + csrc * 16;
  }
  int rA = (wr * 128 + (lane & 15)) * 64 + (((lane >> 4) ^ ((lane >> 1) & 3)) * 16);
  int rB = (wc * 64  + (lane & 15)) * 64 + (((lane >> 4) ^ ((lane >> 1) & 3)) * 16);

  f32x4 zv = {0.f, 0.f, 0.f, 0.f};
  f32x4 acc[8][4];
#pragma unroll
  for (int m = 0; m < 8; ++m)
#pragma unroll
    for (int n = 0; n < 4; ++n) acc[m][n] = zv;
  bf16x8 af[4], bfr[4];

  PROLOGUE();
#pragma unroll 1
  for (int i = 0; i < NI - 1; ++i) {
    size_t kb = (size_t)i * 256;
    ITER_FULL(kb);
  }
  {
    size_t kb = (size_t)(NI - 1) * 256;
    ITER_LAST(kb);
  }

#pragma unroll
  for (int m = 0; m < 8; ++m)
#pragma unroll
    for (int q = 0; q < 4; ++q) {
      int row = wr * 128 + m * 16 + (lane >> 4) * 4 + q;
      if (row >= rows) continue;
      int mi = mbase + row;
      int tok = tok_list[off + mi];
      float wt = tok_w[off + mi];
      float* op = out + (size_t)tok * DDIM + nbase + wc * 64 + (lane & 15);
#pragma unroll
      for (int n = 0; n < 4; ++n)
        atomicAdd(op + n * 16, acc[m][n][q] * wt);
    }
}

extern "C" void kernel_launch(void* const* d_in, const int* in_sizes, int n_in,
                              void* d_out, int out_size, void* d_ws, size_t ws_size,
                              hipStream_t stream) {
  const float* x      = (const float*)d_in[0];
  const float* gate_w = (const float*)d_in[1];
  const float* w1     = (const float*)d_in[2];
  const float* w2     = (const float*)d_in[3];
  const float* w3     = (const float*)d_in[4];
  float* out = (float*)d_out;
  char* ws = (char*)d_ws;

  size_t o = 0;
  int* counts  = (int*)(ws + o);
  int* offsets = counts + 8;
  int* cursor  = counts + 16;
  o += 256;
  int*   route_e = (int*)(ws + o);   o += (size_t)TT * 2 * 4;
  float* route_w = (float*)(ws + o); o += (size_t)TT * 2 * 4;
  int*   tok_list = (int*)(ws + o);  o += (size_t)TT * 2 * 4;
  float* tok_w = (float*)(ws + o);   o += (size_t)TT * 2 * 4;
  unsigned short* xbf = (unsigned short*)(ws + o); o += (size_t)TT * DDIM * 2;
  size_t fixed = o;

  const size_t WSZ = (size_t)HDIM * DDIM;
  const size_t wbf_full = (size_t)NEXP * WSZ * 2;
  const size_t gfull = (size_t)TT * 2 * HDIM * 2;

  hipMemsetAsync(counts, 0, 8 * sizeof(int), stream);
  hipMemsetAsync(out, 0, (size_t)TT * DDIM * sizeof(float), stream);
  cvt_bf16_kernel<<<4096, 256, 0, stream>>>(x, xbf, (long)TT * DDIM / 4);
  gate_kernel<<<TT, 256, 0, stream>>>(x, gate_w, route_e, route_w, counts);
  scan_kernel<<<1, 64, 0, stream>>>(counts, offsets, cursor);
  scatter_kernel<<<(TT + 255) / 256, 256, 0, stream>>>(route_e, route_w, cursor, tok_list, tok_w);

  if (ws_size >= fixed + 3 * wbf_full + gfull) {
    unsigned short* w1b = (unsigned short*)(ws + fixed);
    unsigned short* w3b = w1b + NEXP * WSZ;
    unsigned short* w2t = w3b + NEXP * WSZ;
    unsigned short* gbuf = w2t + NEXP * WSZ;
    cvt_bf16_kernel<<<8192, 256, 0, stream>>>(w1, w1b, (long)(NEXP * WSZ / 4));
    cvt_bf16_kernel<<<8192, 256, 0, stream>>>(w3, w3b, (long)(NEXP * WSZ / 4));
    transpose_w2_kernel<<<dim3(HDIM / 64, DDIM / 64, NEXP), 256, 0, stream>>>(w2, w2t, -1);
    gemm1_kernel<<<MT * NT1 * NEXP, 512, 0, stream>>>(
        xbf, w1b, w3b, tok_list, counts, offsets, gbuf, -1);
    gemm2_kernel<<<MT * NT2 * NEXP, 512, 0, stream>>>(
        gbuf, w2t, tok_list, tok_w, counts, offsets, out, -1);
  } else {
    unsigned short* w1b = (unsigned short*)(ws + fixed);
    unsigned short* w3b = w1b + WSZ;
    unsigned short* w2t = w3b + WSZ;
    unsigned short* gbuf = w2t + WSZ;
    for (int e = 0; e < NEXP; ++e) {
      cvt_bf16_kernel<<<4096, 256, 0, stream>>>(w1 + (size_t)e * WSZ, w1b, (long)(WSZ / 4));
      cvt_bf16_kernel<<<4096, 256, 0, stream>>>(w3 + (size_t)e * WSZ, w3b, (long)(WSZ / 4));
      transpose_w2_kernel<<<dim3(HDIM / 64, DDIM / 64, 1), 256, 0, stream>>>(w2, w2t, e);
      gemm1_kernel<<<MT * NT1, 512, 0, stream>>>(
          xbf, w1b, w3b, tok_list, counts, offsets, gbuf, e);
      gemm2_kernel<<<MT * NT2, 512, 0, stream>>>(
          gbuf, w2t, tok_list, tok_w, counts, offsets, out, e);
    }
  }
}